// Round 1
// baseline (205.245 us; speedup 1.0000x reference)
//
#include <hip/hip_runtime.h>

#define L 256
#define D 256
#define H 8
#define DH 32

static constexpr float NEGV = -4294967296.0f;       // fp32(-(2^32)+1)
static constexpr float INV_SQRT_DH = 0.17677669529663687f;  // 1/sqrt(32)

// ---------------------------------------------------------------------------
// Fused QKV projection: out = A @ W + bias (+ add)
// z=0: Q   = queries@Wq + bq
// z=1: KPk = keys@Wk + bk + absolute_pos_K
// z=2: VPv = keys@Wv + bv + absolute_pos_V
// 64x64 tile, BK=16, 256 threads, 4x4 per thread.
// ---------------------------------------------------------------------------
__global__ __launch_bounds__(256) void proj3_kernel(
    const float* __restrict__ queries, const float* __restrict__ keys,
    const float* __restrict__ Wq, const float* __restrict__ bq,
    const float* __restrict__ Wk, const float* __restrict__ bk,
    const float* __restrict__ Wv, const float* __restrict__ bv,
    const float* __restrict__ pk, const float* __restrict__ pv,
    float* __restrict__ Qo, float* __restrict__ KPko, float* __restrict__ VPvo)
{
    __shared__ float As[16][68];   // [k][m], padded for bank spread, 16B-aligned rows
    __shared__ float Bs[16][64];   // [k][n]

    const float* A; const float* W; const float* bias; const float* add; float* out;
    if (blockIdx.z == 0)      { A = queries; W = Wq; bias = bq; add = nullptr; out = Qo; }
    else if (blockIdx.z == 1) { A = keys;    W = Wk; bias = bk; add = pk;      out = KPko; }
    else                      { A = keys;    W = Wv; bias = bv; add = pv;      out = VPvo; }

    const int t  = threadIdx.x;
    const int bm = blockIdx.x * 64;
    const int bn = blockIdx.y * 64;

    const int ar = t >> 2;            // 0..63 tile row (A load)
    const int ak = (t & 3) << 2;      // k offset (A load)
    const int br = t >> 4;            // 0..15 k row (B load)
    const int bc = (t & 15) << 2;     // col (B load)
    const int tm = (t >> 4) << 2;     // output rows
    const int tn = (t & 15) << 2;     // output cols

    float acc[4][4] = {};

    for (int k0 = 0; k0 < 256; k0 += 16) {
        const float4 a4 = *(const float4*)&A[(bm + ar) * 256 + k0 + ak];
        const float4 b4 = *(const float4*)&W[(k0 + br) * 256 + bn + bc];
        As[ak + 0][ar] = a4.x; As[ak + 1][ar] = a4.y;
        As[ak + 2][ar] = a4.z; As[ak + 3][ar] = a4.w;
        *(float4*)&Bs[br][bc] = b4;
        __syncthreads();

        #pragma unroll
        for (int kk = 0; kk < 16; ++kk) {
            const float4 a = *(const float4*)&As[kk][tm];
            const float4 bb = *(const float4*)&Bs[kk][tn];
            const float aa[4] = {a.x, a.y, a.z, a.w};
            const float bbv[4] = {bb.x, bb.y, bb.z, bb.w};
            #pragma unroll
            for (int i = 0; i < 4; ++i)
                #pragma unroll
                for (int jj = 0; jj < 4; ++jj)
                    acc[i][jj] = fmaf(aa[i], bbv[jj], acc[i][jj]);
        }
        __syncthreads();
    }

    const float4 bias4 = *(const float4*)&bias[bn + tn];
    #pragma unroll
    for (int i = 0; i < 4; ++i) {
        const int row = bm + tm + i;
        float4 o;
        o.x = acc[i][0] + bias4.x; o.y = acc[i][1] + bias4.y;
        o.z = acc[i][2] + bias4.z; o.w = acc[i][3] + bias4.w;
        if (add) {
            const float4 a4 = *(const float4*)&add[row * 256 + bn + tn];
            o.x += a4.x; o.y += a4.y; o.z += a4.z; o.w += a4.w;
        }
        *(float4*)&out[row * 256 + bn + tn] = o;
    }
}

// ---------------------------------------------------------------------------
// Row-sum masks: kmask[b*L+l] = (sum(keys[b,l,:]) != 0), same for queries.
// One wave per row.
// ---------------------------------------------------------------------------
__global__ __launch_bounds__(256) void mask_kernel(
    const float* __restrict__ keys, const float* __restrict__ queries,
    float* __restrict__ kmask, float* __restrict__ qmask)
{
    const int wid  = (blockIdx.x * 256 + threadIdx.x) >> 6;  // 0..4095
    const int lane = threadIdx.x & 63;
    const float* src = (wid < 2048) ? keys : queries;
    const int row = (wid < 2048) ? wid : (wid - 2048);

    const float4 v = *(const float4*)&src[row * 256 + (lane << 2)];
    float s = v.x + v.y + v.z + v.w;
    #pragma unroll
    for (int o = 1; o < 64; o <<= 1) s += __shfl_xor(s, o);
    if (lane == 0) {
        const float m = (s != 0.0f) ? 1.0f : 0.0f;
        if (wid < 2048) kmask[row] = m; else qmask[row] = m;
    }
}

// ---------------------------------------------------------------------------
// Fused attention: one block (256 thr / 4 waves) per (b, q).
// ---------------------------------------------------------------------------
__global__ __launch_bounds__(256) void attn_kernel(
    const float* __restrict__ Qm, const float* __restrict__ KPk,
    const float* __restrict__ VPv, const float* __restrict__ Tk,
    const float* __restrict__ Tv, const float* __restrict__ kmask,
    const float* __restrict__ qmask, const float* __restrict__ queries,
    float* __restrict__ out)
{
    const int bq = blockIdx.x;   // b*L + q
    const int b  = bq >> 8;
    const int q  = bq & 255;
    const int t  = threadIdx.x;

    __shared__ float qrow[D];
    __shared__ float kmrow[L];
    __shared__ float sc[H][L];
    __shared__ int   allneg[H];
    __shared__ float4 red[256];

    qrow[t]  = Qm[bq * D + t];
    kmrow[t] = kmask[(b << 8) + t];
    __syncthreads();

    // ---- Phase B: scores for all 8 heads.  8 lanes per k, float4 per lane.
    const int g = t >> 3;      // k group 0..31
    const int j = t & 7;       // lane in group
    const size_t tkbase = (size_t)bq << 16;   // bq * L * D

    for (int h = 0; h < H; ++h) {
        const int dbase = (h << 5) + (j << 2);
        const float4 qv = *(const float4*)&qrow[dbase];
        #pragma unroll
        for (int kb = 0; kb < L; kb += 32) {
            const int k = kb + g;
            if (k <= q) {
                const float4 kv  = *(const float4*)&KPk[((b << 8) + k) * 256 + dbase];
                const float4 tkv = *(const float4*)&Tk[tkbase + ((size_t)k << 8) + dbase];
                float p = qv.x * (kv.x + tkv.x);
                p = fmaf(qv.y, kv.y + tkv.y, p);
                p = fmaf(qv.z, kv.z + tkv.z, p);
                p = fmaf(qv.w, kv.w + tkv.w, p);
                p += __shfl_xor(p, 1);
                p += __shfl_xor(p, 2);
                p += __shfl_xor(p, 4);
                if (j == 0)
                    sc[h][k] = (kmrow[k] != 0.0f) ? p * INV_SQRT_DH : NEGV;
            } else {
                if (j == 0) sc[h][k] = NEGV;
            }
        }
    }
    __syncthreads();

    // ---- Softmax: wave w handles head rows 2w, 2w+1 (full 256-wide, jax semantics)
    const int w    = t >> 6;
    const int lane = t & 63;
    #pragma unroll
    for (int hh = 0; hh < 2; ++hh) {
        const int h = (w << 1) + hh;
        float v0 = sc[h][lane];
        float v1 = sc[h][lane + 64];
        float v2 = sc[h][lane + 128];
        float v3 = sc[h][lane + 192];
        float m = fmaxf(fmaxf(v0, v1), fmaxf(v2, v3));
        #pragma unroll
        for (int o = 1; o < 64; o <<= 1) m = fmaxf(m, __shfl_xor(m, o));
        const float e0 = __expf(v0 - m), e1 = __expf(v1 - m);
        const float e2 = __expf(v2 - m), e3 = __expf(v3 - m);
        float s = e0 + e1 + e2 + e3;
        #pragma unroll
        for (int o = 1; o < 64; o <<= 1) s += __shfl_xor(s, o);
        const float r = 1.0f / s;
        sc[h][lane]       = e0 * r;
        sc[h][lane + 64]  = e1 * r;
        sc[h][lane + 128] = e2 * r;
        sc[h][lane + 192] = e3 * r;
        if (lane == 0) allneg[h] = (m == NEGV) ? 1 : 0;
    }
    __syncthreads();

    // ---- Phase C: out = attn @ (VPv + Tv), 4-wave k-split, float4 per lane.
    const int dg = lane;          // output dims 4*dg .. 4*dg+3
    const int h  = dg >> 3;
    const size_t tvbase = (size_t)bq << 16;
    const int kmax = allneg[h] ? L : (q + 1);

    float4 acc = make_float4(0.f, 0.f, 0.f, 0.f);
    for (int k = w; k < kmax; k += 4) {
        const float a = sc[h][k];
        const float4 v   = *(const float4*)&VPv[((b << 8) + k) * 256 + (dg << 2)];
        const float4 tvv = *(const float4*)&Tv[tvbase + ((size_t)k << 8) + (dg << 2)];
        acc.x = fmaf(a, v.x + tvv.x, acc.x);
        acc.y = fmaf(a, v.y + tvv.y, acc.y);
        acc.z = fmaf(a, v.z + tvv.z, acc.z);
        acc.w = fmaf(a, v.w + tvv.w, acc.w);
    }
    red[t] = acc;
    __syncthreads();

    if (t < 64) {
        const float4 r0 = red[t], r1 = red[t + 64], r2 = red[t + 128], r3 = red[t + 192];
        const float qmv = qmask[bq];
        const float4 qv = *(const float4*)&queries[bq * 256 + (t << 2)];
        float4 o;
        o.x = (r0.x + r1.x + r2.x + r3.x) * qmv + qv.x;
        o.y = (r0.y + r1.y + r2.y + r3.y) * qmv + qv.y;
        o.z = (r0.z + r1.z + r2.z + r3.z) * qmv + qv.z;
        o.w = (r0.w + r1.w + r2.w + r3.w) * qmv + qv.w;
        *(float4*)&out[bq * 256 + (t << 2)] = o;
    }
}

// ---------------------------------------------------------------------------
extern "C" void kernel_launch(void* const* d_in, const int* in_sizes, int n_in,
                              void* d_out, int out_size, void* d_ws, size_t ws_size,
                              hipStream_t stream)
{
    const float* queries = (const float*)d_in[0];
    const float* keys    = (const float*)d_in[1];
    const float* Tk      = (const float*)d_in[2];
    const float* Tv      = (const float*)d_in[3];
    const float* pk      = (const float*)d_in[4];
    const float* pv      = (const float*)d_in[5];
    const float* Wq      = (const float*)d_in[6];
    const float* bq      = (const float*)d_in[7];
    const float* Wk      = (const float*)d_in[8];
    const float* bk      = (const float*)d_in[9];
    const float* Wv      = (const float*)d_in[10];
    const float* bv      = (const float*)d_in[11];
    float* out = (float*)d_out;

    float* ws  = (float*)d_ws;
    float* Q   = ws;                    // 2048*256
    float* KPk = ws + 524288;           // 2048*256
    float* VPv = ws + 1048576;          // 2048*256
    float* km  = ws + 1572864;          // 2048
    float* qm  = ws + 1574912;          // 2048

    dim3 pgrid(2048 / 64, 256 / 64, 3);
    proj3_kernel<<<pgrid, 256, 0, stream>>>(queries, keys, Wq, bq, Wk, bk,
                                            Wv, bv, pk, pv, Q, KPk, VPv);
    mask_kernel<<<1024, 256, 0, stream>>>(keys, queries, km, qm);
    attn_kernel<<<2048, 256, 0, stream>>>(Q, KPk, VPv, Tk, Tv, km, qm, queries, out);
}

// Round 2
// 200.388 us; speedup vs baseline: 1.0242x; 1.0242x over previous
//
#include <hip/hip_runtime.h>

#define L 256
#define D 256
#define H 8
#define DH 32

static constexpr float NEGV = -4294967296.0f;       // fp32(-(2^32)+1)
static constexpr float INV_SQRT_DH = 0.17677669529663687f;  // 1/sqrt(32)

// ---------------------------------------------------------------------------
// Fused QKV projection: out = A @ W + bias (+ add)
// z=0: Q   = queries@Wq + bq
// z=1: KPk = keys@Wk + bk + absolute_pos_K
// z=2: VPv = keys@Wv + bv + absolute_pos_V
// 64x64 tile, BK=16, 256 threads, 4x4 per thread.
// ---------------------------------------------------------------------------
__global__ __launch_bounds__(256) void proj3_kernel(
    const float* __restrict__ queries, const float* __restrict__ keys,
    const float* __restrict__ Wq, const float* __restrict__ bq,
    const float* __restrict__ Wk, const float* __restrict__ bk,
    const float* __restrict__ Wv, const float* __restrict__ bv,
    const float* __restrict__ pk, const float* __restrict__ pv,
    float* __restrict__ Qo, float* __restrict__ KPko, float* __restrict__ VPvo)
{
    __shared__ float As[16][68];   // [k][m], padded
    __shared__ float Bs[16][64];   // [k][n]

    const float* A; const float* W; const float* bias; const float* add; float* out;
    if (blockIdx.z == 0)      { A = queries; W = Wq; bias = bq; add = nullptr; out = Qo; }
    else if (blockIdx.z == 1) { A = keys;    W = Wk; bias = bk; add = pk;      out = KPko; }
    else                      { A = keys;    W = Wv; bias = bv; add = pv;      out = VPvo; }

    const int t  = threadIdx.x;
    const int bm = blockIdx.x * 64;
    const int bn = blockIdx.y * 64;

    const int ar = t >> 2;            // 0..63 tile row (A load)
    const int ak = (t & 3) << 2;      // k offset (A load)
    const int br = t >> 4;            // 0..15 k row (B load)
    const int bc = (t & 15) << 2;     // col (B load)
    const int tm = (t >> 4) << 2;     // output rows
    const int tn = (t & 15) << 2;     // output cols

    float acc[4][4] = {};

    for (int k0 = 0; k0 < 256; k0 += 16) {
        const float4 a4 = *(const float4*)&A[(bm + ar) * 256 + k0 + ak];
        const float4 b4 = *(const float4*)&W[(k0 + br) * 256 + bn + bc];
        As[ak + 0][ar] = a4.x; As[ak + 1][ar] = a4.y;
        As[ak + 2][ar] = a4.z; As[ak + 3][ar] = a4.w;
        *(float4*)&Bs[br][bc] = b4;
        __syncthreads();

        #pragma unroll
        for (int kk = 0; kk < 16; ++kk) {
            const float4 a = *(const float4*)&As[kk][tm];
            const float4 bb = *(const float4*)&Bs[kk][tn];
            const float aa[4] = {a.x, a.y, a.z, a.w};
            const float bbv[4] = {bb.x, bb.y, bb.z, bb.w};
            #pragma unroll
            for (int i = 0; i < 4; ++i)
                #pragma unroll
                for (int jj = 0; jj < 4; ++jj)
                    acc[i][jj] = fmaf(aa[i], bbv[jj], acc[i][jj]);
        }
        __syncthreads();
    }

    const float4 bias4 = *(const float4*)&bias[bn + tn];
    #pragma unroll
    for (int i = 0; i < 4; ++i) {
        const int row = bm + tm + i;
        float4 o;
        o.x = acc[i][0] + bias4.x; o.y = acc[i][1] + bias4.y;
        o.z = acc[i][2] + bias4.z; o.w = acc[i][3] + bias4.w;
        if (add) {
            const float4 a4 = *(const float4*)&add[row * 256 + bn + tn];
            o.x += a4.x; o.y += a4.y; o.z += a4.z; o.w += a4.w;
        }
        *(float4*)&out[row * 256 + bn + tn] = o;
    }
}

// ---------------------------------------------------------------------------
// Row-sum masks: kmask[b*L+l] = (sum(keys[b,l,:]) != 0), same for queries.
// ---------------------------------------------------------------------------
__global__ __launch_bounds__(256) void mask_kernel(
    const float* __restrict__ keys, const float* __restrict__ queries,
    float* __restrict__ kmask, float* __restrict__ qmask)
{
    const int wid  = (blockIdx.x * 256 + threadIdx.x) >> 6;  // 0..4095
    const int lane = threadIdx.x & 63;
    const float* src = (wid < 2048) ? keys : queries;
    const int row = (wid < 2048) ? wid : (wid - 2048);

    const float4 v = *(const float4*)&src[row * 256 + (lane << 2)];
    float s = v.x + v.y + v.z + v.w;
    #pragma unroll
    for (int o = 1; o < 64; o <<= 1) s += __shfl_xor(s, o);
    if (lane == 0) {
        const float m = (s != 0.0f) ? 1.0f : 0.0f;
        if (wid < 2048) kmask[row] = m; else qmask[row] = m;
    }
}

// ---------------------------------------------------------------------------
// Fused attention: one block (256 thr / 4 waves) per (b, q).
// Phase B: k-outer — one wave reads one FULL Tk row (1 KB contiguous) per
// iteration and produces all 8 heads' scores via 8-lane group reduce.
// ---------------------------------------------------------------------------
#define LP (L + 4)   // pad: stride 260 % 32 = 4 -> 8 heads hit distinct banks

__global__ __launch_bounds__(256) void attn_kernel(
    const float* __restrict__ Qm, const float* __restrict__ KPk,
    const float* __restrict__ VPv, const float* __restrict__ Tk,
    const float* __restrict__ Tv, const float* __restrict__ kmask,
    const float* __restrict__ qmask, const float* __restrict__ queries,
    float* __restrict__ out)
{
    const int bq = blockIdx.x;   // b*L + q
    const int b  = bq >> 8;
    const int q  = bq & 255;
    const int t  = threadIdx.x;
    const int w    = t >> 6;     // wave 0..3
    const int lane = t & 63;

    __shared__ float qrow[D];
    __shared__ float kmrow[L];
    __shared__ float sc[H][LP];
    __shared__ int   allneg[H];
    __shared__ float4 red[256];

    qrow[t]  = Qm[bq * D + t];
    kmrow[t] = kmask[(b << 8) + t];
    #pragma unroll
    for (int i = t; i < H * LP; i += 256) (&sc[0][0])[i] = NEGV;
    __syncthreads();

    // ---- Phase B: scores, linear streaming over Tk rows.
    const int hB = lane >> 3;    // head this lane's group reduces into
    const int jB = lane & 7;     // lane within 8-lane head group
    const size_t tbase = (size_t)bq << 16;   // bq * L * D
    const float4 qv = *(const float4*)&qrow[lane << 2];

    #pragma unroll 2
    for (int k = w; k <= q; k += 4) {
        const float4 kv  = *(const float4*)&KPk[((b << 8) + k) * 256 + (lane << 2)];
        const float4 tkv = *(const float4*)&Tk[tbase + ((size_t)k << 8) + (lane << 2)];
        float p = qv.x * (kv.x + tkv.x);
        p = fmaf(qv.y, kv.y + tkv.y, p);
        p = fmaf(qv.z, kv.z + tkv.z, p);
        p = fmaf(qv.w, kv.w + tkv.w, p);
        p += __shfl_xor(p, 1);
        p += __shfl_xor(p, 2);
        p += __shfl_xor(p, 4);
        if (jB == 0)
            sc[hB][k] = (kmrow[k] != 0.0f) ? p * INV_SQRT_DH : NEGV;
    }
    __syncthreads();

    // ---- Softmax: wave w handles head rows 2w, 2w+1 (jax semantics)
    #pragma unroll
    for (int hh = 0; hh < 2; ++hh) {
        const int h = (w << 1) + hh;
        float v0 = sc[h][lane];
        float v1 = sc[h][lane + 64];
        float v2 = sc[h][lane + 128];
        float v3 = sc[h][lane + 192];
        float m = fmaxf(fmaxf(v0, v1), fmaxf(v2, v3));
        #pragma unroll
        for (int o = 1; o < 64; o <<= 1) m = fmaxf(m, __shfl_xor(m, o));
        const float e0 = __expf(v0 - m), e1 = __expf(v1 - m);
        const float e2 = __expf(v2 - m), e3 = __expf(v3 - m);
        float s = e0 + e1 + e2 + e3;
        #pragma unroll
        for (int o = 1; o < 64; o <<= 1) s += __shfl_xor(s, o);
        const float r = 1.0f / s;
        sc[h][lane]       = e0 * r;
        sc[h][lane + 64]  = e1 * r;
        sc[h][lane + 128] = e2 * r;
        sc[h][lane + 192] = e3 * r;
        if (lane == 0) allneg[h] = (m == NEGV) ? 1 : 0;
    }
    __syncthreads();

    // ---- Phase C: out = attn @ (VPv + Tv), 4-wave k-split, linear rows.
    const int dg = lane;          // output dims 4*dg .. 4*dg+3
    const int h  = dg >> 3;
    const int kmax = allneg[h] ? L : (q + 1);

    float4 acc = make_float4(0.f, 0.f, 0.f, 0.f);
    #pragma unroll 2
    for (int k = w; k < kmax; k += 4) {
        const float a = sc[h][k];
        const float4 v   = *(const float4*)&VPv[((b << 8) + k) * 256 + (dg << 2)];
        const float4 tvv = *(const float4*)&Tv[tbase + ((size_t)k << 8) + (dg << 2)];
        acc.x = fmaf(a, v.x + tvv.x, acc.x);
        acc.y = fmaf(a, v.y + tvv.y, acc.y);
        acc.z = fmaf(a, v.z + tvv.z, acc.z);
        acc.w = fmaf(a, v.w + tvv.w, acc.w);
    }
    red[t] = acc;
    __syncthreads();

    if (t < 64) {
        const float4 r0 = red[t], r1 = red[t + 64], r2 = red[t + 128], r3 = red[t + 192];
        const float qmv = qmask[bq];
        const float4 qv2 = *(const float4*)&queries[bq * 256 + (t << 2)];
        float4 o;
        o.x = (r0.x + r1.x + r2.x + r3.x) * qmv + qv2.x;
        o.y = (r0.y + r1.y + r2.y + r3.y) * qmv + qv2.y;
        o.z = (r0.z + r1.z + r2.z + r3.z) * qmv + qv2.z;
        o.w = (r0.w + r1.w + r2.w + r3.w) * qmv + qv2.w;
        *(float4*)&out[bq * 256 + (t << 2)] = o;
    }
}

// ---------------------------------------------------------------------------
extern "C" void kernel_launch(void* const* d_in, const int* in_sizes, int n_in,
                              void* d_out, int out_size, void* d_ws, size_t ws_size,
                              hipStream_t stream)
{
    const float* queries = (const float*)d_in[0];
    const float* keys    = (const float*)d_in[1];
    const float* Tk      = (const float*)d_in[2];
    const float* Tv      = (const float*)d_in[3];
    const float* pk      = (const float*)d_in[4];
    const float* pv      = (const float*)d_in[5];
    const float* Wq      = (const float*)d_in[6];
    const float* bq      = (const float*)d_in[7];
    const float* Wk      = (const float*)d_in[8];
    const float* bk      = (const float*)d_in[9];
    const float* Wv      = (const float*)d_in[10];
    const float* bv      = (const float*)d_in[11];
    float* out = (float*)d_out;

    float* ws  = (float*)d_ws;
    float* Q   = ws;                    // 2048*256
    float* KPk = ws + 524288;           // 2048*256
    float* VPv = ws + 1048576;          // 2048*256
    float* km  = ws + 1572864;          // 2048
    float* qm  = ws + 1574912;          // 2048

    dim3 pgrid(2048 / 64, 256 / 64, 3);
    proj3_kernel<<<pgrid, 256, 0, stream>>>(queries, keys, Wq, bq, Wk, bk,
                                            Wv, bv, pk, pv, Q, KPk, VPv);
    mask_kernel<<<1024, 256, 0, stream>>>(keys, queries, km, qm);
    attn_kernel<<<2048, 256, 0, stream>>>(Q, KPk, VPv, Tk, Tv, km, qm, queries, out);
}

// Round 3
// 146.233 us; speedup vs baseline: 1.4035x; 1.3703x over previous
//
#include <hip/hip_runtime.h>

#define L 256
#define D 256
#define H 8
#define DH 32

static constexpr float NEGV = -4294967296.0f;       // fp32(-(2^32)+1)
static constexpr float INV_SQRT_DH = 0.17677669529663687f;  // 1/sqrt(32)

// ---------------------------------------------------------------------------
// Fused QKV projection: out = A @ W + bias (+ add)
// z=0: Q   = queries@Wq + bq
// z=1: KPk = keys@Wk + bk + absolute_pos_K
// z=2: VPv = keys@Wv + bv + absolute_pos_V
// 64x64 tile, BK=16, 256 threads, 4x4 per thread.
// ---------------------------------------------------------------------------
__global__ __launch_bounds__(256) void proj3_kernel(
    const float* __restrict__ queries, const float* __restrict__ keys,
    const float* __restrict__ Wq, const float* __restrict__ bq,
    const float* __restrict__ Wk, const float* __restrict__ bk,
    const float* __restrict__ Wv, const float* __restrict__ bv,
    const float* __restrict__ pk, const float* __restrict__ pv,
    float* __restrict__ Qo, float* __restrict__ KPko, float* __restrict__ VPvo)
{
    __shared__ float As[16][68];   // [k][m], padded
    __shared__ float Bs[16][64];   // [k][n]

    const float* A; const float* W; const float* bias; const float* add; float* out;
    if (blockIdx.z == 0)      { A = queries; W = Wq; bias = bq; add = nullptr; out = Qo; }
    else if (blockIdx.z == 1) { A = keys;    W = Wk; bias = bk; add = pk;      out = KPko; }
    else                      { A = keys;    W = Wv; bias = bv; add = pv;      out = VPvo; }

    const int t  = threadIdx.x;
    const int bm = blockIdx.x * 64;
    const int bn = blockIdx.y * 64;

    const int ar = t >> 2;            // 0..63 tile row (A load)
    const int ak = (t & 3) << 2;      // k offset (A load)
    const int br = t >> 4;            // 0..15 k row (B load)
    const int bc = (t & 15) << 2;     // col (B load)
    const int tm = (t >> 4) << 2;     // output rows
    const int tn = (t & 15) << 2;     // output cols

    float acc[4][4] = {};

    for (int k0 = 0; k0 < 256; k0 += 16) {
        const float4 a4 = *(const float4*)&A[(bm + ar) * 256 + k0 + ak];
        const float4 b4 = *(const float4*)&W[(k0 + br) * 256 + bn + bc];
        As[ak + 0][ar] = a4.x; As[ak + 1][ar] = a4.y;
        As[ak + 2][ar] = a4.z; As[ak + 3][ar] = a4.w;
        *(float4*)&Bs[br][bc] = b4;
        __syncthreads();

        #pragma unroll
        for (int kk = 0; kk < 16; ++kk) {
            const float4 a = *(const float4*)&As[kk][tm];
            const float4 bb = *(const float4*)&Bs[kk][tn];
            const float aa[4] = {a.x, a.y, a.z, a.w};
            const float bbv[4] = {bb.x, bb.y, bb.z, bb.w};
            #pragma unroll
            for (int i = 0; i < 4; ++i)
                #pragma unroll
                for (int jj = 0; jj < 4; ++jj)
                    acc[i][jj] = fmaf(aa[i], bbv[jj], acc[i][jj]);
        }
        __syncthreads();
    }

    const float4 bias4 = *(const float4*)&bias[bn + tn];
    #pragma unroll
    for (int i = 0; i < 4; ++i) {
        const int row = bm + tm + i;
        float4 o;
        o.x = acc[i][0] + bias4.x; o.y = acc[i][1] + bias4.y;
        o.z = acc[i][2] + bias4.z; o.w = acc[i][3] + bias4.w;
        if (add) {
            const float4 a4 = *(const float4*)&add[row * 256 + bn + tn];
            o.x += a4.x; o.y += a4.y; o.z += a4.z; o.w += a4.w;
        }
        *(float4*)&out[row * 256 + bn + tn] = o;
    }
}

// ---------------------------------------------------------------------------
// Row-sum masks: kmask[b*L+l] = (sum(keys[b,l,:]) != 0), same for queries.
// ---------------------------------------------------------------------------
__global__ __launch_bounds__(256) void mask_kernel(
    const float* __restrict__ keys, const float* __restrict__ queries,
    float* __restrict__ kmask, float* __restrict__ qmask)
{
    const int wid  = (blockIdx.x * 256 + threadIdx.x) >> 6;  // 0..4095
    const int lane = threadIdx.x & 63;
    const float* src = (wid < 2048) ? keys : queries;
    const int row = (wid < 2048) ? wid : (wid - 2048);

    const float4 v = *(const float4*)&src[row * 256 + (lane << 2)];
    float s = v.x + v.y + v.z + v.w;
    #pragma unroll
    for (int o = 1; o < 64; o <<= 1) s += __shfl_xor(s, o);
    if (lane == 0) {
        const float m = (s != 0.0f) ? 1.0f : 0.0f;
        if (wid < 2048) kmask[row] = m; else qmask[row] = m;
    }
}

// ---------------------------------------------------------------------------
// Fused attention: one block (256 thr / 4 waves) per (b, q).
// Load-balance remap: q = (b&1) ? 255-j : j, so any round-robin-ish
// CU assignment gets paired (q, 255-q) blocks -> constant work per CU.
// ---------------------------------------------------------------------------
#define LP (L + 4)   // pad: stride 260 -> 8 heads in distinct banks

__global__ __launch_bounds__(256) void attn_kernel(
    const float* __restrict__ Qm, const float* __restrict__ KPk,
    const float* __restrict__ VPv, const float* __restrict__ Tk,
    const float* __restrict__ Tv, const float* __restrict__ kmask,
    const float* __restrict__ qmask, const float* __restrict__ queries,
    float* __restrict__ out)
{
    const int bid = blockIdx.x;
    const int b   = bid >> 8;
    const int j0  = bid & 255;
    const int q   = (b & 1) ? (255 - j0) : j0;   // balance causal work per CU
    const int bq  = (b << 8) + q;
    const int t  = threadIdx.x;
    const int w    = t >> 6;     // wave 0..3
    const int lane = t & 63;

    __shared__ float qrow[D];
    __shared__ float kmrow[L];
    __shared__ float sc[H][LP];
    __shared__ int   allneg[H];
    __shared__ float4 red[256];

    qrow[t]  = Qm[bq * D + t];
    kmrow[t] = kmask[(b << 8) + t];
    #pragma unroll
    for (int i = t; i < H * LP; i += 256) (&sc[0][0])[i] = NEGV;
    __syncthreads();

    // ---- Phase B: scores, linear streaming over Tk rows.
    const int hB = lane >> 3;    // head this lane's group reduces into
    const int jB = lane & 7;     // lane within 8-lane head group
    const size_t tbase = (size_t)bq << 16;   // bq * L * D
    const float4 qv = *(const float4*)&qrow[lane << 2];

    #pragma unroll 2
    for (int k = w; k <= q; k += 4) {
        const float4 kv  = *(const float4*)&KPk[((b << 8) + k) * 256 + (lane << 2)];
        const float4 tkv = *(const float4*)&Tk[tbase + ((size_t)k << 8) + (lane << 2)];
        float p = qv.x * (kv.x + tkv.x);
        p = fmaf(qv.y, kv.y + tkv.y, p);
        p = fmaf(qv.z, kv.z + tkv.z, p);
        p = fmaf(qv.w, kv.w + tkv.w, p);
        p += __shfl_xor(p, 1);
        p += __shfl_xor(p, 2);
        p += __shfl_xor(p, 4);
        if (jB == 0)
            sc[hB][k] = (kmrow[k] != 0.0f) ? p * INV_SQRT_DH : NEGV;
    }
    __syncthreads();

    // ---- Softmax: wave w handles head rows 2w, 2w+1 (jax semantics)
    #pragma unroll
    for (int hh = 0; hh < 2; ++hh) {
        const int h = (w << 1) + hh;
        float v0 = sc[h][lane];
        float v1 = sc[h][lane + 64];
        float v2 = sc[h][lane + 128];
        float v3 = sc[h][lane + 192];
        float m = fmaxf(fmaxf(v0, v1), fmaxf(v2, v3));
        #pragma unroll
        for (int o = 1; o < 64; o <<= 1) m = fmaxf(m, __shfl_xor(m, o));
        const float e0 = __expf(v0 - m), e1 = __expf(v1 - m);
        const float e2 = __expf(v2 - m), e3 = __expf(v3 - m);
        float s = e0 + e1 + e2 + e3;
        #pragma unroll
        for (int o = 1; o < 64; o <<= 1) s += __shfl_xor(s, o);
        const float r = 1.0f / s;
        sc[h][lane]       = e0 * r;
        sc[h][lane + 64]  = e1 * r;
        sc[h][lane + 128] = e2 * r;
        sc[h][lane + 192] = e3 * r;
        if (lane == 0) allneg[h] = (m == NEGV) ? 1 : 0;
    }
    __syncthreads();

    // ---- Phase C: out = attn @ (VPv + Tv), 4-wave k-split, linear rows.
    const int dg = lane;          // output dims 4*dg .. 4*dg+3
    const int h  = dg >> 3;
    const int kmax = allneg[h] ? L : (q + 1);

    float4 acc = make_float4(0.f, 0.f, 0.f, 0.f);
    #pragma unroll 2
    for (int k = w; k < kmax; k += 4) {
        const float a = sc[h][k];
        const float4 v   = *(const float4*)&VPv[((b << 8) + k) * 256 + (dg << 2)];
        const float4 tvv = *(const float4*)&Tv[tbase + ((size_t)k << 8) + (dg << 2)];
        acc.x = fmaf(a, v.x + tvv.x, acc.x);
        acc.y = fmaf(a, v.y + tvv.y, acc.y);
        acc.z = fmaf(a, v.z + tvv.z, acc.z);
        acc.w = fmaf(a, v.w + tvv.w, acc.w);
    }
    red[t] = acc;
    __syncthreads();

    if (t < 64) {
        const float4 r0 = red[t], r1 = red[t + 64], r2 = red[t + 128], r3 = red[t + 192];
        const float qmv = qmask[bq];
        const float4 qv2 = *(const float4*)&queries[bq * 256 + (t << 2)];
        float4 o;
        o.x = (r0.x + r1.x + r2.x + r3.x) * qmv + qv2.x;
        o.y = (r0.y + r1.y + r2.y + r3.y) * qmv + qv2.y;
        o.z = (r0.z + r1.z + r2.z + r3.z) * qmv + qv2.z;
        o.w = (r0.w + r1.w + r2.w + r3.w) * qmv + qv2.w;
        *(float4*)&out[bq * 256 + (t << 2)] = o;
    }
}

// ---------------------------------------------------------------------------
extern "C" void kernel_launch(void* const* d_in, const int* in_sizes, int n_in,
                              void* d_out, int out_size, void* d_ws, size_t ws_size,
                              hipStream_t stream)
{
    const float* queries = (const float*)d_in[0];
    const float* keys    = (const float*)d_in[1];
    const float* Tk      = (const float*)d_in[2];
    const float* Tv      = (const float*)d_in[3];
    const float* pk      = (const float*)d_in[4];
    const float* pv      = (const float*)d_in[5];
    const float* Wq      = (const float*)d_in[6];
    const float* bq      = (const float*)d_in[7];
    const float* Wk      = (const float*)d_in[8];
    const float* bk      = (const float*)d_in[9];
    const float* Wv      = (const float*)d_in[10];
    const float* bv      = (const float*)d_in[11];
    float* out = (float*)d_out;

    float* ws  = (float*)d_ws;
    float* Q   = ws;                    // 2048*256
    float* KPk = ws + 524288;           // 2048*256
    float* VPv = ws + 1048576;          // 2048*256
    float* km  = ws + 1572864;          // 2048
    float* qm  = ws + 1574912;          // 2048

    dim3 pgrid(2048 / 64, 256 / 64, 3);
    proj3_kernel<<<pgrid, 256, 0, stream>>>(queries, keys, Wq, bq, Wk, bk,
                                            Wv, bv, pk, pv, Q, KPk, VPv);
    mask_kernel<<<1024, 256, 0, stream>>>(keys, queries, km, qm);
    attn_kernel<<<2048, 256, 0, stream>>>(Q, KPk, VPv, Tk, Tv, km, qm, queries, out);
}